// Round 1
// 134.954 us; speedup vs baseline: 1.1407x; 1.1407x over previous
//
#include <hip/hip_runtime.h>

// SIRD RK4, round 14: packed-FP32 (VOP3P) RK4 core, 22 -> 15 slots/tstep.
// State held as a VGPR pair q = (sigma, I), sigma = c*S. Each RK4 stage:
//   u = v_pk_mul_f32(q, q) op_sel cross-swap        -> (m, m),  m = sigma*I
//   d = v_pk_fma_f32((0,-gm), q, u)                 -> (m, g),  g = -gm*I + m
//   q' = v_pk_fma_f32((coefS, coefI), d, q)         -> stage state
// Accumulation: acc = pk_fma(2,d2,d1); acc = pk_fma(2,d3,acc);
//               q = pk_fma(W, acc, q); q = pk_fma(W, d4, q).
// Every half-lane op is the identical IEEE fma in the identical order as the
// round-13 scalar macro -> output is bit-identical to the passing kernel.
// Producer: 2x15 pk + 1 ds_write_b64 per k (15.5 slots/tstep, was 23.5).
// Consumer: ds_read_b64 + D-invariant + bit-identical recompute (hidden).
//
// D from RK4-preserved invariant: D = fma(-kD/c, sigma, fma(-kD, I, kD*N)).

#define N_POP 1.0e7f
#define T_PTS 2048
#define KSEG 32                  // LDS slots per segment
#define SEG_T (KSEG * 2)         // tsteps covered per segment (stride 2)
#define NSEG (T_PTS / SEG_T)     // 32 segments

typedef float f2 __attribute__((ext_vector_type(2)));

// One RK4 step (h=1) on packed state Q = (sigma, I): 15 VOP3P slots.
// %0=Q  %1=u  %2=qs  %3=d1  %4=d2  %5=d3  %6=d4
// %7=KA=(0,-gm)  %8=C2=(-c/2,1/2)  %9=C4=(-c,1)  %10=W6=(-c/6,1/6)  %11=TWO
#define RK4_PK(Q, KA, C2, C4, W6, TWO)                                        \
    do {                                                                      \
        f2 u_, qs_, d1_, d2_, d3_, d4_;                                       \
        asm("v_pk_mul_f32 %1, %0, %0 op_sel:[0,1] op_sel_hi:[1,0]\n\t"        \
            "v_pk_fma_f32 %3, %7, %0, %1\n\t"                                 \
            "v_pk_fma_f32 %2, %8, %3, %0\n\t"                                 \
            "v_pk_mul_f32 %1, %2, %2 op_sel:[0,1] op_sel_hi:[1,0]\n\t"        \
            "v_pk_fma_f32 %4, %7, %2, %1\n\t"                                 \
            "v_pk_fma_f32 %2, %8, %4, %0\n\t"                                 \
            "v_pk_mul_f32 %1, %2, %2 op_sel:[0,1] op_sel_hi:[1,0]\n\t"        \
            "v_pk_fma_f32 %5, %7, %2, %1\n\t"                                 \
            "v_pk_fma_f32 %2, %9, %5, %0\n\t"                                 \
            "v_pk_mul_f32 %1, %2, %2 op_sel:[0,1] op_sel_hi:[1,0]\n\t"        \
            "v_pk_fma_f32 %6, %7, %2, %1\n\t"                                 \
            "v_pk_fma_f32 %3, %11, %4, %3\n\t"                                \
            "v_pk_fma_f32 %3, %11, %5, %3\n\t"                                \
            "v_pk_fma_f32 %0, %10, %3, %0\n\t"                                \
            "v_pk_fma_f32 %0, %10, %6, %0"                                    \
            : "+v"(Q), "=&v"(u_), "=&v"(qs_), "=&v"(d1_), "=&v"(d2_),         \
              "=&v"(d3_), "=&v"(d4_)                                          \
            : "v"(KA), "v"(C2), "v"(C4), "v"(W6), "v"(TWO));                  \
    } while (0)

__global__ __launch_bounds__(128, 1) void sird_kernel(const float* __restrict__ alpha,
                                                      float* __restrict__ out) {
    const int lane = threadIdx.x & 63;
    const int wave = threadIdx.x >> 6;        // 0 = producer, 1 = consumer
    const int s = blockIdx.x * 64 + lane;     // scenario (same for both waves)

    // Double-buffered packed state: [buf][slot][lane]. 32 KiB.
    __shared__ f2 buf[2][KSEG][64];

    const float beta  = alpha[s * 3 + 0];
    const float gamma = alpha[s * 3 + 1];
    const float mu    = alpha[s * 3 + 2];

    const float c    = beta * (1.0f / N_POP);
    const float gm   = gamma + mu;
    const float w    = 1.0f / 6.0f;
    const float kD   = mu / gm;               // gamma,mu > 0 a.s.
    const float kDN  = kD * (float)N_POP;
    const float nkc  = -kD / c;
    const float nk   = -kD;

    // VOP3P coefficient pairs (lo half acts on sigma, hi half on I).
    f2 KA  = {0.0f, -gm};                     // d = KA*q + (m,m) -> (m, g)
    f2 C2  = {-0.5f * c, 0.5f};               // half-step coefs
    f2 C4  = {-c, 1.0f};                      // full-step coefs
    f2 W6  = {-c * w, w};                     // weighted-sum coefs
    f2 TWO = {2.0f, 2.0f};

    f2 q = {c * (N_POP - 1.0f), 1.0f};        // (sigma0, I0)

    float2* __restrict__ orow = (float2*)out + (size_t)s * T_PTS;

    for (int seg = 0; seg <= NSEG; ++seg) {
        if (wave == 0) {
            if (seg < NSEG) {
                f2* b = &buf[seg & 1][0][lane];
#pragma unroll
                for (int k = 0; k < KSEG; ++k) {
                    b[k * 64] = q;             // one ds_write_b64, imm offset
                    RK4_PK(q, KA, C2, C4, W6, TWO);   // even -> odd
                    RK4_PK(q, KA, C2, C4, W6, TWO);   // odd  -> next even
                }
            }
        } else {
            if (seg >= 1) {
                const f2* rb = &buf[(seg - 1) & 1][0][lane];
                float2* op = orow + (size_t)(seg - 1) * SEG_T;
#pragma unroll
                for (int k = 0; k < KSEG; ++k) {
                    f2 qv = rb[k * 64];        // one ds_read_b64
                    const float D0 = __builtin_fmaf(nkc, qv.x,
                                     __builtin_fmaf(nk, qv.y, kDN));
                    op[2 * k] = make_float2(qv.y, D0);
                    RK4_PK(qv, KA, C2, C4, W6, TWO);  // bit-identical odd t
                    const float D1 = __builtin_fmaf(nkc, qv.x,
                                     __builtin_fmaf(nk, qv.y, kDN));
                    op[2 * k + 1] = make_float2(qv.y, D1);
                }
            }
        }
        __syncthreads();
    }
}

extern "C" void kernel_launch(void* const* d_in, const int* in_sizes, int n_in,
                              void* d_out, int out_size, void* d_ws, size_t ws_size,
                              hipStream_t stream) {
    const float* alpha = (const float*)d_in[0];
    float* out = (float*)d_out;
    sird_kernel<<<dim3(T_PTS / 64), dim3(128), 0, stream>>>(alpha, out);
}